// Round 4
// baseline (316.229 us; speedup 1.0000x reference)
//
#include <hip/hip_runtime.h>
#include <stdint.h>

#define Bn 16
#define Sn 2048
#define Dn 128
#define QBLK 64
#define KVBLK 64
#define NT (Sn / KVBLK)

typedef __attribute__((ext_vector_type(4))) float f32x4;
typedef __attribute__((ext_vector_type(8))) short bf16x8;   // 8 bf16 = 4 VGPRs
typedef __attribute__((ext_vector_type(2))) unsigned int u32x2;

// LDS layout (bytes), double-buffered K/VT:
//  buf b (b=0,1) at base b*34816:
//    K  : [64][128] bf16 row-major, swizzled byte(k,d) = (k*256+d*2) ^ ((k&7)<<4)   16384 B
//    VT : [128][72] bf16 (V^T, row stride 144 B): byte(d,k) = d*144 + k*2           18432 B
//  P  : per-wave [16][72] bf16, row stride 144 B: byte(q,k) = q*144 + k*2         4*2304 B
#define BUFSZ 34816
#define VTOFF 16384
#define POFF 69632
#define SMEM_BYTES 78848

__device__ __forceinline__ uint32_t f2bf_u(float f) {   // fp32 -> bf16 bits, RNE
  uint32_t x = __float_as_uint(f);
  return (x + 0x7fffu + ((x >> 16) & 1u)) >> 16;
}

__global__ __launch_bounds__(256, 2) void attn_fwd(
    const float* __restrict__ Q, const float* __restrict__ K,
    const float* __restrict__ V, float* __restrict__ O) {
  __shared__ uint4 smem_[SMEM_BYTES / 16];
  char* smem = (char*)smem_;

  const int tid = threadIdx.x;
  const int lane = tid & 63;
  const int w = tid >> 6;        // wave id 0..3
  const int g = lane >> 4;       // 16-lane group 0..3
  const int c = lane & 15;
  const int b = blockIdx.y;
  const int q0 = blockIdx.x * QBLK;

  // ---- Q fragments: A-operand layout, row = lane%16, k = (lane/16)*8 + j (+32*kk) ----
  const float qscale = 0.08838834764831845f * 1.44269504088896340736f; // 1/sqrt(128)*log2e
  bf16x8 qf[4];
  {
    const float* qrow = Q + ((size_t)(b * Sn + q0 + w * 16 + c)) * Dn;
#pragma unroll
    for (int kk = 0; kk < 4; ++kk) {
      const float4 a = *(const float4*)(qrow + g * 8 + kk * 32);
      const float4 d = *(const float4*)(qrow + g * 8 + kk * 32 + 4);
      bf16x8 q8;
      q8[0] = (short)f2bf_u(a.x * qscale); q8[1] = (short)f2bf_u(a.y * qscale);
      q8[2] = (short)f2bf_u(a.z * qscale); q8[3] = (short)f2bf_u(a.w * qscale);
      q8[4] = (short)f2bf_u(d.x * qscale); q8[5] = (short)f2bf_u(d.y * qscale);
      q8[6] = (short)f2bf_u(d.z * qscale); q8[7] = (short)f2bf_u(d.w * qscale);
      qf[kk] = q8;
    }
  }

  f32x4 acc[8];
#pragma unroll
  for (int i = 0; i < 8; ++i) acc[i] = (f32x4){0.f, 0.f, 0.f, 0.f};
  float m_r[4], l_r[4];
#pragma unroll
  for (int r = 0; r < 4; ++r) { m_r[r] = -3.0e38f; l_r[r] = 0.f; }

  const float4* Kg4 = (const float4*)(K + (size_t)b * Sn * Dn);
  const float* Vg_base = V + (size_t)b * Sn * Dn;
  const uint32_t pbase = POFF + w * 2304;
  const int vd = tid & 127;      // V-transpose: this thread owns column d=vd
  const int vkb = tid >> 7;      // and k-subblock 0/1

  // staging registers — short lifetime (one phase), not across the whole tile
  float4 kreg[8];
  float vreg[32];

#define ISSUE_K(kv_)                                                           \
  {                                                                            \
    const int kvrow4 = (kv_) * (Dn / 4);                                       \
    _Pragma("unroll") for (int it = 0; it < 8; ++it) {                         \
      const int gr = it * 256 + tid;                                           \
      kreg[it] = Kg4[kvrow4 + (gr >> 5) * 32 + (gr & 31)];                     \
    }                                                                          \
  }

#define COMMIT_K(dstb_)                                                        \
  {                                                                            \
    _Pragma("unroll") for (int it = 0; it < 8; ++it) {                         \
      const int gr = it * 256 + tid;                                           \
      const int k = gr >> 5;                                                   \
      const int dg = gr & 31;                                                  \
      u32x2 wv;                                                                \
      wv.x = f2bf_u(kreg[it].x) | (f2bf_u(kreg[it].y) << 16);                  \
      wv.y = f2bf_u(kreg[it].z) | (f2bf_u(kreg[it].w) << 16);                  \
      uint32_t koffb = (uint32_t)(k * 256 + dg * 8) ^ (uint32_t)((k & 7) << 4);\
      *(u32x2*)(smem + (dstb_) + koffb) = wv;                                  \
    }                                                                          \
  }

#define ISSUE_V(kv_)                                                           \
  {                                                                            \
    const float* Vg = Vg_base + (size_t)(kv_)*Dn;                              \
    _Pragma("unroll") for (int it = 0; it < 4; ++it) {                         \
      const int k0 = vkb * 8 + it * 16;                                        \
      _Pragma("unroll") for (int j = 0; j < 8; ++j)                            \
          vreg[it * 8 + j] = Vg[(k0 + j) * Dn + vd];                           \
    }                                                                          \
  }

#define COMMIT_V(dstb_)                                                        \
  {                                                                            \
    _Pragma("unroll") for (int it = 0; it < 4; ++it) {                         \
      const int k0 = vkb * 8 + it * 16;                                        \
      uint4 pk;                                                                \
      pk.x = f2bf_u(vreg[it * 8 + 0]) | (f2bf_u(vreg[it * 8 + 1]) << 16);      \
      pk.y = f2bf_u(vreg[it * 8 + 2]) | (f2bf_u(vreg[it * 8 + 3]) << 16);      \
      pk.z = f2bf_u(vreg[it * 8 + 4]) | (f2bf_u(vreg[it * 8 + 5]) << 16);      \
      pk.w = f2bf_u(vreg[it * 8 + 6]) | (f2bf_u(vreg[it * 8 + 7]) << 16);      \
      *(uint4*)(smem + (dstb_) + VTOFF + vd * 144 + k0 * 2) = pk;              \
    }                                                                          \
  }

  // prologue: stage tile 0 into buf 0
  ISSUE_K(0)
  COMMIT_K(0)
  ISSUE_V(0)
  COMMIT_V(0)
  __syncthreads();

#pragma unroll 2
  for (int t = 0; t < NT; ++t) {
    const uint32_t cb = (uint32_t)(t & 1) * BUFSZ;   // current buffer base
    const uint32_t nb = BUFSZ - cb;                  // next buffer base
    const bool pf = (t < NT - 1);

    // ---- issue K(t+1) loads; latency hides under QK^T ----
    if (pf) ISSUE_K((t + 1) * KVBLK)

    // ---- QK^T: S[16 q][64 k], 4 col-frags x 4 k-steps ----
    f32x4 sv[4];
#pragma unroll
    for (int kf = 0; kf < 4; ++kf) {
      f32x4 s = (f32x4){0.f, 0.f, 0.f, 0.f};
      const int row = kf * 16 + c;   // key index = B-operand col (lane%16)
#pragma unroll
      for (int kk = 0; kk < 4; ++kk) {
        uint32_t off = (uint32_t)(row * 256 + g * 16 + kk * 64) ^
                       (uint32_t)((row & 7) << 4);
        bf16x8 kb = *(const bf16x8*)(smem + cb + off);
        s = __builtin_amdgcn_mfma_f32_16x16x32_bf16(qf[kk], kb, s, 0, 0, 0);
      }
      sv[kf] = s;
    }

    // ---- commit K(t+1) to the other buffer; issue V(t+1) loads ----
    if (pf) {
      COMMIT_K(nb)
      ISSUE_V((t + 1) * KVBLK)
    }

    // ---- online softmax (C-layout: lane owns rows 4g+r, col c, per col-frag) ----
    float rmax[4];
#pragma unroll
    for (int r = 0; r < 4; ++r)
      rmax[r] = fmaxf(fmaxf(sv[0][r], sv[1][r]), fmaxf(sv[2][r], sv[3][r]));
#pragma unroll
    for (int r = 0; r < 4; ++r) {
#pragma unroll
      for (int msk = 1; msk < 16; msk <<= 1)
        rmax[r] = fmaxf(rmax[r], __shfl_xor(rmax[r], msk, 64));
    }
    float alpha[4], mnew[4];
#pragma unroll
    for (int r = 0; r < 4; ++r) {
      mnew[r] = fmaxf(m_r[r], rmax[r]);
      alpha[r] = __builtin_amdgcn_exp2f(m_r[r] - mnew[r]);
      m_r[r] = mnew[r];
    }
    float rsum[4] = {0.f, 0.f, 0.f, 0.f};
#pragma unroll
    for (int kf = 0; kf < 4; ++kf) {
#pragma unroll
      for (int r = 0; r < 4; ++r) {
        float p = __builtin_amdgcn_exp2f(sv[kf][r] - mnew[r]);
        rsum[r] += p;
        const int prow = g * 4 + r;
        uint32_t poffb = (uint32_t)(prow * 144 + (kf * 16 + c) * 2);
        *(unsigned short*)(smem + pbase + poffb) = (unsigned short)f2bf_u(p);
      }
    }
#pragma unroll
    for (int r = 0; r < 4; ++r) {
#pragma unroll
      for (int msk = 1; msk < 16; msk <<= 1)
        rsum[r] += __shfl_xor(rsum[r], msk, 64);
      l_r[r] = l_r[r] * alpha[r] + rsum[r];
    }
    f32x4 av;
    av[0] = alpha[0]; av[1] = alpha[1]; av[2] = alpha[2]; av[3] = alpha[3];
#pragma unroll
    for (int i = 0; i < 8; ++i) acc[i] *= av;

    // ---- commit V(t+1) ----
    if (pf) COMMIT_V(nb)

    // P store -> P load: same wave; LDS ops per-wave are in-order. Fence compiler.
    asm volatile("" ::: "memory");

    // ---- P fragments (A-operand) from per-wave P_lds ----
    bf16x8 pa[2];
#pragma unroll
    for (int kk2 = 0; kk2 < 2; ++kk2) {
      uint32_t off = (uint32_t)(c * 144 + g * 16 + kk2 * 64);
      pa[kk2] = *(const bf16x8*)(smem + pbase + off);
    }

    // ---- PV: O[16 q][128 d] += P[16][64] * V[64][128], V read from VT rows ----
#pragma unroll
    for (int df = 0; df < 8; ++df) {
      const int dcol = df * 16 + c;
      bf16x8 v0 = *(const bf16x8*)(smem + cb + VTOFF + dcol * 144 + g * 16);
      bf16x8 v1 = *(const bf16x8*)(smem + cb + VTOFF + dcol * 144 + g * 16 + 64);
      acc[df] = __builtin_amdgcn_mfma_f32_16x16x32_bf16(pa[0], v0, acc[df], 0, 0, 0);
      acc[df] = __builtin_amdgcn_mfma_f32_16x16x32_bf16(pa[1], v1, acc[df], 0, 0, 0);
    }

    // one barrier per tile: readers of buf(t) done AND writers of buf(t+1) done
    __syncthreads();
  }

  // ---- epilogue: normalize and store fp32 ----
  float invl[4];
#pragma unroll
  for (int r = 0; r < 4; ++r) invl[r] = 1.0f / l_r[r];
  float* orow = O + ((size_t)(b * Sn + q0 + w * 16 + g * 4)) * Dn;
#pragma unroll
  for (int r = 0; r < 4; ++r) {
#pragma unroll
    for (int df = 0; df < 8; ++df) {
      orow[r * Dn + df * 16 + c] = acc[df][r] * invl[r];
    }
  }
}

extern "C" void kernel_launch(void* const* d_in, const int* in_sizes, int n_in,
                              void* d_out, int out_size, void* d_ws, size_t ws_size,
                              hipStream_t stream) {
  (void)in_sizes; (void)n_in; (void)d_ws; (void)ws_size; (void)out_size;
  const float* Q = (const float*)d_in[0];
  const float* K = (const float*)d_in[1];
  const float* V = (const float*)d_in[2];
  float* O = (float*)d_out;
  dim3 grid(Sn / QBLK, Bn, 1);
  attn_fwd<<<grid, dim3(256, 1, 1), 0, stream>>>(Q, K, V, O);
}

// Round 5
// 256.268 us; speedup vs baseline: 1.2340x; 1.2340x over previous
//
#include <hip/hip_runtime.h>
#include <stdint.h>

#define Bn 16
#define Sn 2048
#define Dn 128
#define QBLK 64
#define KVBLK 64

typedef __attribute__((ext_vector_type(4))) float f32x4;
typedef __attribute__((ext_vector_type(8))) short bf16x8;   // 8 bf16 = 4 VGPRs
typedef __attribute__((ext_vector_type(2))) unsigned int u32x2;

// LDS layout (bytes):
//  K  : [64][128] bf16, swizzled  byte(k,d) = (k*256 + d*2) ^ ((k&7)<<4)      16384 B
//  VT : [128][68] bf16 (V^T, row stride 136 B): byte(d,k) = d*136 + k*2      17408 B
//  P  : OVERLAYS K region (safe: barrier between QK^T reads and P writes);
//       per-wave [16] rows, stride 136: base = w*2176, byte(q,k)=q*136+k*2  4*2176 B
#define VTOFF 16384
#define SMEM_BYTES 33792

__device__ __forceinline__ uint32_t f2bf_u(float f) {   // fp32 -> bf16 bits, RNE
  uint32_t x = __float_as_uint(f);
  return (x + 0x7fffu + ((x >> 16) & 1u)) >> 16;
}

// SPLIT=true : blockIdx.z = KV half; write UNNORMALIZED acc + (m,l) per row.
// SPLIT=false: full KV range; normalize and write O directly.
template <bool SPLIT>
__global__ __launch_bounds__(256, 4) void attn_fwd(
    const float* __restrict__ Q, const float* __restrict__ K,
    const float* __restrict__ V, float* __restrict__ O0,
    float* __restrict__ O1, float2* __restrict__ ml0,
    float2* __restrict__ ml1) {
  __shared__ uint4 smem_[SMEM_BYTES / 16];
  char* smem = (char*)smem_;

  const int tid = threadIdx.x;
  const int lane = tid & 63;
  const int w = tid >> 6;        // wave id 0..3
  const int g = lane >> 4;       // 16-lane group 0..3
  const int c = lane & 15;
  const int b = blockIdx.y;
  const int q0 = blockIdx.x * QBLK;
  const int kvh = SPLIT ? blockIdx.z : 0;
  const int ntiles = SPLIT ? (Sn / 2) / KVBLK : Sn / KVBLK;
  const int kvbase = kvh * (Sn / 2);

  // ---- Q fragments: A-operand, row = lane%16, k = (lane/16)*8 + j (+32*kk) ----
  const float qscale = 0.08838834764831845f * 1.44269504088896340736f; // 1/sqrt(128)*log2e
  bf16x8 qf[4];
  {
    const float* qrow = Q + ((size_t)(b * Sn + q0 + w * 16 + c)) * Dn;
#pragma unroll
    for (int kk = 0; kk < 4; ++kk) {
      const float4 a = *(const float4*)(qrow + g * 8 + kk * 32);
      const float4 d = *(const float4*)(qrow + g * 8 + kk * 32 + 4);
      bf16x8 q8;
      q8[0] = (short)f2bf_u(a.x * qscale); q8[1] = (short)f2bf_u(a.y * qscale);
      q8[2] = (short)f2bf_u(a.z * qscale); q8[3] = (short)f2bf_u(a.w * qscale);
      q8[4] = (short)f2bf_u(d.x * qscale); q8[5] = (short)f2bf_u(d.y * qscale);
      q8[6] = (short)f2bf_u(d.z * qscale); q8[7] = (short)f2bf_u(d.w * qscale);
      qf[kk] = q8;
    }
  }

  f32x4 acc[8];
#pragma unroll
  for (int i = 0; i < 8; ++i) acc[i] = (f32x4){0.f, 0.f, 0.f, 0.f};
  float m_r[4], l_r[4];
#pragma unroll
  for (int r = 0; r < 4; ++r) { m_r[r] = -3.0e38f; l_r[r] = 0.f; }

  const float4* Kg4 = (const float4*)(K + (size_t)b * Sn * Dn);
  const float* Vg_base = V + (size_t)b * Sn * Dn;
  const uint32_t pbase = (uint32_t)(w * 2176);   // P overlays K region
  const int vd = tid & 127;      // V-transpose: this thread owns column d=vd
  const int vkb = tid >> 7;      // and k-subblock 0/1

  for (int t = 0; t < ntiles; ++t) {
    const int kv = kvbase + t * KVBLK;
    __syncthreads();   // prev tile's P/VT reads done; K region free for staging

    // ---- stage K tile: fp32 global (float4, coalesced) -> bf16 swizzled LDS ----
    {
      const int kvrow4 = kv * (Dn / 4);
#pragma unroll
      for (int it = 0; it < 8; ++it) {
        const int gr = it * 256 + tid;
        const int k = gr >> 5;
        const int dg = gr & 31;
        float4 kvv = Kg4[kvrow4 + k * 32 + dg];
        u32x2 wv;
        wv.x = f2bf_u(kvv.x) | (f2bf_u(kvv.y) << 16);
        wv.y = f2bf_u(kvv.z) | (f2bf_u(kvv.w) << 16);
        uint32_t koffb = (uint32_t)(k * 256 + dg * 8) ^ (uint32_t)((k & 7) << 4);
        *(u32x2*)(smem + koffb) = wv;
      }
    }
    // ---- stage V tile TRANSPOSED: VT[d][k], row stride 136 B ----
    {
      const float* Vg = Vg_base + (size_t)kv * Dn;
#pragma unroll
      for (int it = 0; it < 4; ++it) {
        const int k0 = vkb * 8 + it * 16;
        uint4 pk;
        {
          float v0 = Vg[(k0 + 0) * Dn + vd], v1 = Vg[(k0 + 1) * Dn + vd];
          float v2 = Vg[(k0 + 2) * Dn + vd], v3 = Vg[(k0 + 3) * Dn + vd];
          float v4 = Vg[(k0 + 4) * Dn + vd], v5 = Vg[(k0 + 5) * Dn + vd];
          float v6 = Vg[(k0 + 6) * Dn + vd], v7 = Vg[(k0 + 7) * Dn + vd];
          pk.x = f2bf_u(v0) | (f2bf_u(v1) << 16);
          pk.y = f2bf_u(v2) | (f2bf_u(v3) << 16);
          pk.z = f2bf_u(v4) | (f2bf_u(v5) << 16);
          pk.w = f2bf_u(v6) | (f2bf_u(v7) << 16);
        }
        *(uint4*)(smem + VTOFF + vd * 136 + k0 * 2) = pk;
      }
    }
    __syncthreads();

    // ---- QK^T: S[16 q][64 k], 4 col-frags x 4 k-steps ----
    f32x4 sv[4];
#pragma unroll
    for (int kf = 0; kf < 4; ++kf) {
      f32x4 s = (f32x4){0.f, 0.f, 0.f, 0.f};
      const int row = kf * 16 + c;   // key index = B-operand col (lane%16)
#pragma unroll
      for (int kk = 0; kk < 4; ++kk) {
        uint32_t off = (uint32_t)(row * 256 + g * 16 + kk * 64) ^
                       (uint32_t)((row & 7) << 4);
        bf16x8 kb = *(const bf16x8*)(smem + off);
        s = __builtin_amdgcn_mfma_f32_16x16x32_bf16(qf[kk], kb, s, 0, 0, 0);
      }
      sv[kf] = s;
    }

    __syncthreads();   // ALL waves' K reads done -> K region reusable as P

    // ---- online softmax (C-layout: lane owns rows 4g+r, col c, per col-frag) ----
    float rmax[4];
#pragma unroll
    for (int r = 0; r < 4; ++r)
      rmax[r] = fmaxf(fmaxf(sv[0][r], sv[1][r]), fmaxf(sv[2][r], sv[3][r]));
#pragma unroll
    for (int r = 0; r < 4; ++r) {
#pragma unroll
      for (int msk = 1; msk < 16; msk <<= 1)
        rmax[r] = fmaxf(rmax[r], __shfl_xor(rmax[r], msk, 64));
    }
    float alpha[4], mnew[4];
#pragma unroll
    for (int r = 0; r < 4; ++r) {
      mnew[r] = fmaxf(m_r[r], rmax[r]);
      alpha[r] = __builtin_amdgcn_exp2f(m_r[r] - mnew[r]);
      m_r[r] = mnew[r];
    }
    float rsum[4] = {0.f, 0.f, 0.f, 0.f};
#pragma unroll
    for (int kf = 0; kf < 4; ++kf) {
#pragma unroll
      for (int r = 0; r < 4; ++r) {
        float p = __builtin_amdgcn_exp2f(sv[kf][r] - mnew[r]);
        rsum[r] += p;
        const int prow = g * 4 + r;
        uint32_t poffb = (uint32_t)(prow * 136 + (kf * 16 + c) * 2);
        *(unsigned short*)(smem + pbase + poffb) = (unsigned short)f2bf_u(p);
      }
    }
#pragma unroll
    for (int r = 0; r < 4; ++r) {
#pragma unroll
      for (int msk = 1; msk < 16; msk <<= 1)
        rsum[r] += __shfl_xor(rsum[r], msk, 64);
      l_r[r] = l_r[r] * alpha[r] + rsum[r];
    }
    f32x4 av;
    av[0] = alpha[0]; av[1] = alpha[1]; av[2] = alpha[2]; av[3] = alpha[3];
#pragma unroll
    for (int i = 0; i < 8; ++i) acc[i] *= av;

    // P store -> P load: same wave; per-wave LDS ops are in-order. Fence compiler.
    asm volatile("" ::: "memory");

    // ---- P fragments (A-operand) from per-wave P slice ----
    bf16x8 pa[2];
#pragma unroll
    for (int kk2 = 0; kk2 < 2; ++kk2) {
      uint32_t off = (uint32_t)(c * 136 + g * 16 + kk2 * 64);
      pa[kk2] = *(const bf16x8*)(smem + pbase + off);
    }

    // ---- PV: O[16 q][128 d] += P[16][64] * V[64][128], V read from VT rows ----
#pragma unroll
    for (int df = 0; df < 8; ++df) {
      const int dcol = df * 16 + c;
      bf16x8 v0 = *(const bf16x8*)(smem + VTOFF + dcol * 136 + g * 16);
      bf16x8 v1 = *(const bf16x8*)(smem + VTOFF + dcol * 136 + g * 16 + 64);
      acc[df] = __builtin_amdgcn_mfma_f32_16x16x32_bf16(pa[0], v0, acc[df], 0, 0, 0);
      acc[df] = __builtin_amdgcn_mfma_f32_16x16x32_bf16(pa[1], v1, acc[df], 0, 0, 0);
    }
  }

  // ---- epilogue ----
  float* Op = (SPLIT && kvh) ? O1 : O0;
  if (SPLIT) {
    // unnormalized partial + (m,l)
    float2* ml = kvh ? ml1 : ml0;
    const int rowb = b * Sn + q0 + w * 16 + g * 4;
    float* orow = Op + (size_t)rowb * Dn;
#pragma unroll
    for (int r = 0; r < 4; ++r) {
#pragma unroll
      for (int df = 0; df < 8; ++df)
        orow[r * Dn + df * 16 + c] = acc[df][r];
      if (c == 0) ml[rowb + r] = make_float2(m_r[r], l_r[r]);
    }
  } else {
    float invl[4];
#pragma unroll
    for (int r = 0; r < 4; ++r) invl[r] = 1.0f / l_r[r];
    float* orow = Op + ((size_t)(b * Sn + q0 + w * 16 + g * 4)) * Dn;
#pragma unroll
    for (int r = 0; r < 4; ++r) {
#pragma unroll
      for (int df = 0; df < 8; ++df)
        orow[r * Dn + df * 16 + c] = acc[df][r] * invl[r];
    }
  }
}

__global__ __launch_bounds__(256) void attn_combine(
    float* __restrict__ O, const float* __restrict__ O1,
    const float2* __restrict__ ml0, const float2* __restrict__ ml1) {
  const int e = blockIdx.x * 256 + threadIdx.x;   // one float4 per thread
  const int row = e >> 5;
  const float2 a = ml0[row];
  const float2 bb = ml1[row];
  const float M = fmaxf(a.x, bb.x);
  const float w0 = __builtin_amdgcn_exp2f(a.x - M);
  const float w1 = __builtin_amdgcn_exp2f(bb.x - M);
  const float inv = 1.0f / (w0 * a.y + w1 * bb.y);
  const float s0 = w0 * inv, s1 = w1 * inv;
  f32x4 o0 = ((const f32x4*)O)[e];
  f32x4 o1 = ((const f32x4*)O1)[e];
  ((f32x4*)O)[e] = o0 * s0 + o1 * s1;
}

extern "C" void kernel_launch(void* const* d_in, const int* in_sizes, int n_in,
                              void* d_out, int out_size, void* d_ws, size_t ws_size,
                              hipStream_t stream) {
  (void)in_sizes; (void)n_in; (void)out_size;
  const float* Q = (const float*)d_in[0];
  const float* K = (const float*)d_in[1];
  const float* V = (const float*)d_in[2];
  float* O = (float*)d_out;

  const size_t nO = (size_t)Bn * Sn * Dn;          // 4,194,304 floats
  const size_t needB = nO * 4 + (size_t)Bn * Sn * 8 * 2;  // O1 + ml0 + ml1

  if (ws_size >= needB) {
    float* O1 = (float*)d_ws;
    float2* ml0 = (float2*)((char*)d_ws + nO * 4);
    float2* ml1 = ml0 + (size_t)Bn * Sn;
    dim3 grid(Sn / QBLK, Bn, 2);
    attn_fwd<true><<<grid, dim3(256, 1, 1), 0, stream>>>(Q, K, V, O, O1, ml0, ml1);
    const int nblk = (int)(nO / 4 / 256);          // 4096
    attn_combine<<<nblk, 256, 0, stream>>>(O, O1, ml0, ml1);
  } else {
    dim3 grid(Sn / QBLK, Bn, 1);
    attn_fwd<false><<<grid, dim3(256, 1, 1), 0, stream>>>(Q, K, V, O, nullptr,
                                                          nullptr, nullptr);
  }
}

// Round 6
// 222.989 us; speedup vs baseline: 1.4181x; 1.1492x over previous
//
#include <hip/hip_runtime.h>
#include <stdint.h>

#define Bn 16
#define Sn 2048
#define Dn 128
#define QBLK 128
#define KVBLK 64
#define NWAVE 8
#define NTHR (NWAVE * 64)

typedef __attribute__((ext_vector_type(4))) float f32x4;
typedef __attribute__((ext_vector_type(8))) short bf16x8;   // 8 bf16 = 4 VGPRs
typedef __attribute__((ext_vector_type(2))) unsigned int u32x2;

// LDS layout (bytes):
//  K  : [64][128] bf16, swizzled  byte(k,d) = (k*256 + d*2) ^ ((k&7)<<4)      16384 B
//  VT : [128][68] bf16 (V^T, row stride 136 B): byte(d,k) = d*136 + k*2      17408 B
//  P  : per-wave [16] rows, stride 136: base = POFF + w*2176                8*2176 B
#define VTOFF 16384
#define POFF 33792
#define SMEM_BYTES 51200

__device__ __forceinline__ uint32_t f2bf_u(float f) {   // fp32 -> bf16 bits, RNE
  uint32_t x = __float_as_uint(f);
  return (x + 0x7fffu + ((x >> 16) & 1u)) >> 16;
}

__global__ __launch_bounds__(NTHR, 2) void attn_fwd(
    const float* __restrict__ Q, const float* __restrict__ K,
    const float* __restrict__ V, float* __restrict__ O) {
  __shared__ uint4 smem_[SMEM_BYTES / 16];
  char* smem = (char*)smem_;

  const int tid = threadIdx.x;
  const int lane = tid & 63;
  const int w = tid >> 6;        // wave id 0..7
  const int g = lane >> 4;       // 16-lane group 0..3
  const int c = lane & 15;
  const int b = blockIdx.y;
  const int q0 = blockIdx.x * QBLK;

  // ---- Q fragments: A-operand, row = lane%16, k = (lane/16)*8 + j (+32*kk) ----
  const float qscale = 0.08838834764831845f * 1.44269504088896340736f; // 1/sqrt(128)*log2e
  bf16x8 qf[4];
  {
    const float* qrow = Q + ((size_t)(b * Sn + q0 + w * 16 + c)) * Dn;
#pragma unroll
    for (int kk = 0; kk < 4; ++kk) {
      const float4 a = *(const float4*)(qrow + g * 8 + kk * 32);
      const float4 d = *(const float4*)(qrow + g * 8 + kk * 32 + 4);
      bf16x8 q8;
      q8[0] = (short)f2bf_u(a.x * qscale); q8[1] = (short)f2bf_u(a.y * qscale);
      q8[2] = (short)f2bf_u(a.z * qscale); q8[3] = (short)f2bf_u(a.w * qscale);
      q8[4] = (short)f2bf_u(d.x * qscale); q8[5] = (short)f2bf_u(d.y * qscale);
      q8[6] = (short)f2bf_u(d.z * qscale); q8[7] = (short)f2bf_u(d.w * qscale);
      qf[kk] = q8;
    }
  }

  f32x4 acc[8];
#pragma unroll
  for (int i = 0; i < 8; ++i) acc[i] = (f32x4){0.f, 0.f, 0.f, 0.f};
  float m_r[4], l_r[4];
#pragma unroll
  for (int r = 0; r < 4; ++r) { m_r[r] = -3.0e38f; l_r[r] = 0.f; }

  const float4* Kg4 = (const float4*)(K + (size_t)b * Sn * Dn);
  const float* Vg_base = V + (size_t)b * Sn * Dn;
  const uint32_t pbase = (uint32_t)(POFF + w * 2176);
  const int vd = tid & 127;      // V-transpose: this thread owns column d=vd
  const int vkb = tid >> 7;      // k-subblock 0..3

  for (int kv = 0; kv < Sn; kv += KVBLK) {
    __syncthreads();   // all waves done reading previous tile's K/VT/P

    // ---- stage K tile: fp32 global (float4, coalesced) -> bf16 swizzled LDS ----
    {
      const int kvrow4 = kv * (Dn / 4);
#pragma unroll
      for (int it = 0; it < 4; ++it) {
        const int gr = it * NTHR + tid;   // 0..2047
        const int k = gr >> 5;
        const int dg = gr & 31;
        float4 kvv = Kg4[kvrow4 + k * 32 + dg];
        u32x2 wv;
        wv.x = f2bf_u(kvv.x) | (f2bf_u(kvv.y) << 16);
        wv.y = f2bf_u(kvv.z) | (f2bf_u(kvv.w) << 16);
        uint32_t koffb = (uint32_t)(k * 256 + dg * 8) ^ (uint32_t)((k & 7) << 4);
        *(u32x2*)(smem + koffb) = wv;
      }
    }
    // ---- stage V tile TRANSPOSED: VT[d][k], row stride 136 B ----
    {
      const float* Vg = Vg_base + (size_t)kv * Dn;
#pragma unroll
      for (int it = 0; it < 2; ++it) {
        const int k0 = vkb * 8 + it * 32;
        uint4 pk;
        {
          float v0 = Vg[(k0 + 0) * Dn + vd], v1 = Vg[(k0 + 1) * Dn + vd];
          float v2 = Vg[(k0 + 2) * Dn + vd], v3 = Vg[(k0 + 3) * Dn + vd];
          float v4 = Vg[(k0 + 4) * Dn + vd], v5 = Vg[(k0 + 5) * Dn + vd];
          float v6 = Vg[(k0 + 6) * Dn + vd], v7 = Vg[(k0 + 7) * Dn + vd];
          pk.x = f2bf_u(v0) | (f2bf_u(v1) << 16);
          pk.y = f2bf_u(v2) | (f2bf_u(v3) << 16);
          pk.z = f2bf_u(v4) | (f2bf_u(v5) << 16);
          pk.w = f2bf_u(v6) | (f2bf_u(v7) << 16);
        }
        *(uint4*)(smem + VTOFF + vd * 136 + k0 * 2) = pk;
      }
    }
    __syncthreads();

    // ---- QK^T: S[16 q][64 k], 4 col-frags x 4 k-steps ----
    f32x4 sv[4];
#pragma unroll
    for (int kf = 0; kf < 4; ++kf) {
      f32x4 s = (f32x4){0.f, 0.f, 0.f, 0.f};
      const int row = kf * 16 + c;   // key index = B-operand col (lane%16)
#pragma unroll
      for (int kk = 0; kk < 4; ++kk) {
        uint32_t off = (uint32_t)(row * 256 + g * 16 + kk * 64) ^
                       (uint32_t)((row & 7) << 4);
        bf16x8 kb = *(const bf16x8*)(smem + off);
        s = __builtin_amdgcn_mfma_f32_16x16x32_bf16(qf[kk], kb, s, 0, 0, 0);
      }
      sv[kf] = s;
    }

    // ---- online softmax (C-layout: lane owns rows 4g+r, col c, per col-frag) ----
    float rmax[4];
#pragma unroll
    for (int r = 0; r < 4; ++r)
      rmax[r] = fmaxf(fmaxf(sv[0][r], sv[1][r]), fmaxf(sv[2][r], sv[3][r]));
#pragma unroll
    for (int r = 0; r < 4; ++r) {
#pragma unroll
      for (int msk = 1; msk < 16; msk <<= 1)
        rmax[r] = fmaxf(rmax[r], __shfl_xor(rmax[r], msk, 64));
    }
    float alpha[4], mnew[4];
#pragma unroll
    for (int r = 0; r < 4; ++r) {
      mnew[r] = fmaxf(m_r[r], rmax[r]);
      alpha[r] = __builtin_amdgcn_exp2f(m_r[r] - mnew[r]);
      m_r[r] = mnew[r];
    }
    float rsum[4] = {0.f, 0.f, 0.f, 0.f};
#pragma unroll
    for (int kf = 0; kf < 4; ++kf) {
#pragma unroll
      for (int r = 0; r < 4; ++r) {
        float p = __builtin_amdgcn_exp2f(sv[kf][r] - mnew[r]);
        rsum[r] += p;
        const int prow = g * 4 + r;
        uint32_t poffb = (uint32_t)(prow * 136 + (kf * 16 + c) * 2);
        *(unsigned short*)(smem + pbase + poffb) = (unsigned short)f2bf_u(p);
      }
    }
#pragma unroll
    for (int r = 0; r < 4; ++r) {
#pragma unroll
      for (int msk = 1; msk < 16; msk <<= 1)
        rsum[r] += __shfl_xor(rsum[r], msk, 64);
      l_r[r] = l_r[r] * alpha[r] + rsum[r];
    }
    f32x4 av;
    av[0] = alpha[0]; av[1] = alpha[1]; av[2] = alpha[2]; av[3] = alpha[3];
#pragma unroll
    for (int i = 0; i < 8; ++i) acc[i] *= av;

    // P store -> P load: same wave; per-wave LDS ops are in-order. Fence compiler.
    asm volatile("" ::: "memory");

    // ---- P fragments (A-operand) from per-wave P slice ----
    bf16x8 pa[2];
#pragma unroll
    for (int kk2 = 0; kk2 < 2; ++kk2) {
      uint32_t off = (uint32_t)(c * 136 + g * 16 + kk2 * 64);
      pa[kk2] = *(const bf16x8*)(smem + pbase + off);
    }

    // ---- PV: O[16 q][128 d] += P[16][64] * V[64][128], V read from VT rows ----
#pragma unroll
    for (int df = 0; df < 8; ++df) {
      const int dcol = df * 16 + c;
      bf16x8 v0 = *(const bf16x8*)(smem + VTOFF + dcol * 136 + g * 16);
      bf16x8 v1 = *(const bf16x8*)(smem + VTOFF + dcol * 136 + g * 16 + 64);
      acc[df] = __builtin_amdgcn_mfma_f32_16x16x32_bf16(pa[0], v0, acc[df], 0, 0, 0);
      acc[df] = __builtin_amdgcn_mfma_f32_16x16x32_bf16(pa[1], v1, acc[df], 0, 0, 0);
    }
  }

  // ---- epilogue: normalize and store fp32 ----
  float invl[4];
#pragma unroll
  for (int r = 0; r < 4; ++r) invl[r] = 1.0f / l_r[r];
  float* orow = O + ((size_t)(b * Sn + q0 + w * 16 + g * 4)) * Dn;
#pragma unroll
  for (int r = 0; r < 4; ++r) {
#pragma unroll
    for (int df = 0; df < 8; ++df) {
      orow[r * Dn + df * 16 + c] = acc[df][r] * invl[r];
    }
  }
}

extern "C" void kernel_launch(void* const* d_in, const int* in_sizes, int n_in,
                              void* d_out, int out_size, void* d_ws, size_t ws_size,
                              hipStream_t stream) {
  (void)in_sizes; (void)n_in; (void)d_ws; (void)ws_size; (void)out_size;
  const float* Q = (const float*)d_in[0];
  const float* K = (const float*)d_in[1];
  const float* V = (const float*)d_in[2];
  float* O = (float*)d_out;
  dim3 grid(Sn / QBLK, Bn, 1);
  attn_fwd<<<grid, dim3(NTHR, 1, 1), 0, stream>>>(Q, K, V, O);
}

// Round 7
// 187.053 us; speedup vs baseline: 1.6906x; 1.1921x over previous
//
#include <hip/hip_runtime.h>
#include <stdint.h>

#define Bn 16
#define Sn 2048
#define Dn 128
#define QBLK 128
#define KVBLK 64
#define NTHR 256

typedef __attribute__((ext_vector_type(4))) float f32x4;
typedef __attribute__((ext_vector_type(16))) float f32x16;
typedef __attribute__((ext_vector_type(8))) short bf16x8;   // 8 bf16 = 4 VGPRs
typedef __attribute__((ext_vector_type(2))) unsigned int u32x2;

// LDS layout (bytes):
//  K  : [64] rows, stride 264 B (128 bf16 + 4 pad bf16): byte(k,d) = k*264 + 2d
//       -> dword-bank = (66k + c) % 32 = (2k + c) % 32 : 2-way on 32-row reads (free)
//  VT : [128] rows, stride 136 B (V transposed): byte(d,k) = d*136 + 2k : 2-way
#define KSTRIDE 264
#define VTOFF 16896
#define VSTRIDE 136
#define SMEM_BYTES (16896 + 17408)   // 34304

__device__ __forceinline__ uint32_t f2bf_u(float f) {   // fp32 -> bf16 bits, RNE
  uint32_t x = __float_as_uint(f);
  return (x + 0x7fffu + ((x >> 16) & 1u)) >> 16;
}
__device__ __forceinline__ uint32_t pk2(float a, float b) {
  return f2bf_u(a) | (f2bf_u(b) << 16);
}

__global__ __launch_bounds__(NTHR, 1) void attn_fwd(
    const float* __restrict__ Q, const float* __restrict__ K,
    const float* __restrict__ V, float* __restrict__ O) {
  __shared__ uint4 smem_[SMEM_BYTES / 16];
  char* smem = (char*)smem_;

  const int tid = threadIdx.x;
  const int lane = tid & 63;
  const int w = tid >> 6;        // wave 0..3, owns q-rows [q0+32w, q0+32w+32)
  const int hi = lane >> 5;      // half-wave 0/1
  const int ql = lane & 31;      // q within wave-tile; also k-row / d-row selector
  const int b = blockIdx.y;
  const int q0 = blockIdx.x * QBLK;
  const int qg = q0 + w * 32 + ql;

  // ---- Q in registers: B-operand of swapped QK^T. col=q=lane&31, kd=8*hi+j ----
  const float qscale = 0.08838834764831845f * 1.44269504088896340736f; // 1/sqrt(128)*log2e
  bf16x8 qf[8];
  {
    const float* qrow = Q + (size_t)(b * Sn + qg) * Dn;
#pragma unroll
    for (int dk = 0; dk < 8; ++dk) {
      const int d0 = dk * 16 + hi * 8;
      const float4 a = *(const float4*)(qrow + d0);
      const float4 d = *(const float4*)(qrow + d0 + 4);
      bf16x8 q8;
      q8[0] = (short)f2bf_u(a.x * qscale); q8[1] = (short)f2bf_u(a.y * qscale);
      q8[2] = (short)f2bf_u(a.z * qscale); q8[3] = (short)f2bf_u(a.w * qscale);
      q8[4] = (short)f2bf_u(d.x * qscale); q8[5] = (short)f2bf_u(d.y * qscale);
      q8[6] = (short)f2bf_u(d.z * qscale); q8[7] = (short)f2bf_u(d.w * qscale);
      qf[dk] = q8;
    }
  }

  // O^T accumulators: o[dt] is D-tile dt (32 d-rows x 32 q-cols), col=q=lane&31
  f32x16 o[4];
#pragma unroll
  for (int dt = 0; dt < 4; ++dt) {
#pragma unroll
    for (int j = 0; j < 16; ++j) o[dt][j] = 0.f;
  }
  float m_r = -1.0e30f, l_r = 0.f;

  const float4* Kg4 = (const float4*)(K + (size_t)b * Sn * Dn);
  const float* Vg_base = V + (size_t)b * Sn * Dn;
  const int vd = tid & 127;      // VT staging: this thread owns column d=vd
  const int vkb = tid >> 7;      // k-subblock 0/1

  for (int kv = 0; kv < Sn; kv += KVBLK) {
    __syncthreads();   // everyone done reading previous tile

    // ---- stage K: [64][128] fp32 -> bf16 rows @ stride 264 ----
    {
      const int kvrow4 = kv * (Dn / 4);
#pragma unroll
      for (int it = 0; it < 8; ++it) {
        const int gr = it * NTHR + tid;   // 8B granule id, 0..2047
        const int k = gr >> 5;
        const int dg = gr & 31;
        float4 kvv = Kg4[kvrow4 + k * 32 + dg];
        u32x2 wv;
        wv.x = f2bf_u(kvv.x) | (f2bf_u(kvv.y) << 16);
        wv.y = f2bf_u(kvv.z) | (f2bf_u(kvv.w) << 16);
        *(u32x2*)(smem + k * KSTRIDE + dg * 8) = wv;
      }
    }
    // ---- stage V transposed: VT[d][k], row stride 136 ----
    {
      const float* Vg = Vg_base + (size_t)kv * Dn;
#pragma unroll
      for (int it = 0; it < 4; ++it) {
        const int k0 = vkb * 8 + it * 16;
        uint4 pk;
        {
          float v0 = Vg[(k0 + 0) * Dn + vd], v1 = Vg[(k0 + 1) * Dn + vd];
          float v2 = Vg[(k0 + 2) * Dn + vd], v3 = Vg[(k0 + 3) * Dn + vd];
          float v4 = Vg[(k0 + 4) * Dn + vd], v5 = Vg[(k0 + 5) * Dn + vd];
          float v6 = Vg[(k0 + 6) * Dn + vd], v7 = Vg[(k0 + 7) * Dn + vd];
          pk.x = pk2(v0, v1); pk.y = pk2(v2, v3);
          pk.z = pk2(v4, v5); pk.w = pk2(v6, v7);
        }
        *(uint4*)(smem + VTOFF + vd * VSTRIDE + k0 * 2) = pk;
      }
    }
    __syncthreads();

    // ---- swapped QK^T: S^T[k][q] = K·Q^T, two 32x32 tiles (kt=0,1) over k ----
    f32x16 s0, s1;
#pragma unroll
    for (int j = 0; j < 16; ++j) { s0[j] = 0.f; s1[j] = 0.f; }
#pragma unroll
    for (int dk = 0; dk < 8; ++dk) {
      const uint32_t co = (uint32_t)(dk * 32 + hi * 16);
      bf16x8 a0 = *(const bf16x8*)(smem + (ql)*KSTRIDE + co);
      bf16x8 a1 = *(const bf16x8*)(smem + (32 + ql) * KSTRIDE + co);
      s0 = __builtin_amdgcn_mfma_f32_32x32x16_bf16(a0, qf[dk], s0, 0, 0, 0);
      s1 = __builtin_amdgcn_mfma_f32_32x32x16_bf16(a1, qf[dk], s1, 0, 0, 0);
    }
    // lane holds, for q = ql: k = 32*kt + (r&3) + 8*(r>>2) + 4*hi, r = 0..15

    // ---- in-register online softmax (per-lane scalar state) ----
    float x0 = fmaxf(fmaxf(s0[0], s0[1]), fmaxf(s0[2], s0[3]));
    float x1 = fmaxf(fmaxf(s0[4], s0[5]), fmaxf(s0[6], s0[7]));
    float x2 = fmaxf(fmaxf(s0[8], s0[9]), fmaxf(s0[10], s0[11]));
    float x3 = fmaxf(fmaxf(s0[12], s0[13]), fmaxf(s0[14], s0[15]));
    float y0 = fmaxf(fmaxf(s1[0], s1[1]), fmaxf(s1[2], s1[3]));
    float y1 = fmaxf(fmaxf(s1[4], s1[5]), fmaxf(s1[6], s1[7]));
    float y2 = fmaxf(fmaxf(s1[8], s1[9]), fmaxf(s1[10], s1[11]));
    float y3 = fmaxf(fmaxf(s1[12], s1[13]), fmaxf(s1[14], s1[15]));
    float pm = fmaxf(fmaxf(fmaxf(x0, x1), fmaxf(x2, x3)),
                     fmaxf(fmaxf(y0, y1), fmaxf(y2, y3)));
    pm = fmaxf(pm, __shfl_xor(pm, 32, 64));   // combine k-halves (partner lane)

    // defer-max (T13): rescale only when the running max grows by > 8 (exp2 dom.)
    if (!__all(pm <= m_r + 8.0f)) {
      const float mnew = fmaxf(m_r, pm);
      const float alpha = __builtin_amdgcn_exp2f(m_r - mnew);
      l_r *= alpha;
#pragma unroll
      for (int dt = 0; dt < 4; ++dt) o[dt] *= alpha;
      m_r = mnew;
    }

    float p0[16], p1[16];
#pragma unroll
    for (int j = 0; j < 16; ++j) p0[j] = __builtin_amdgcn_exp2f(s0[j] - m_r);
#pragma unroll
    for (int j = 0; j < 16; ++j) p1[j] = __builtin_amdgcn_exp2f(s1[j] - m_r);
    {
      float r0 = 0.f, r1 = 0.f, r2 = 0.f, r3 = 0.f;
#pragma unroll
      for (int j = 0; j < 4; ++j) {
        r0 += p0[j] + p1[j];
        r1 += p0[4 + j] + p1[4 + j];
        r2 += p0[8 + j] + p1[8 + j];
        r3 += p0[12 + j] + p1[12 + j];
      }
      float rsum = (r0 + r1) + (r2 + r3);
      l_r += rsum + __shfl_xor(rsum, 32, 64);
    }

    // ---- pack P to bf16 + half-exchange with lane^32 -> PV B-fragments ----
    // own[kt][m][e] packs p[kt][4m+2e], p[kt][4m+2e+1]  (kk = 8m + 4*hi + ...)
    uint32_t own[2][4][2];
#pragma unroll
    for (int m = 0; m < 4; ++m) {
      own[0][m][0] = pk2(p0[4 * m + 0], p0[4 * m + 1]);
      own[0][m][1] = pk2(p0[4 * m + 2], p0[4 * m + 3]);
      own[1][m][0] = pk2(p1[4 * m + 0], p1[4 * m + 1]);
      own[1][m][1] = pk2(p1[4 * m + 2], p1[4 * m + 3]);
    }
    // send the half the partner needs; receive the half we need
    uint32_t rcv[2][2][2];
#pragma unroll
    for (int kt = 0; kt < 2; ++kt)
#pragma unroll
      for (int j = 0; j < 2; ++j)
#pragma unroll
        for (int e = 0; e < 2; ++e) {
          uint32_t sel = hi ? own[kt][2 * j][e] : own[kt][2 * j + 1][e];
          rcv[kt][j][e] = (uint32_t)__shfl_xor((int)sel, 32, 64);
        }
    // B-frag[ks]: col=q=lane&31, kd=8*hi+j -> k = 16*ks + 8*hi + j
    bf16x8 pb[4];
#pragma unroll
    for (int ks = 0; ks < 4; ++ks) {
      const int kt = ks >> 1, j = ks & 1;
      union { uint32_t u[4]; bf16x8 v; } t;
      t.u[0] = hi ? rcv[kt][j][0] : own[kt][2 * j][0];
      t.u[1] = hi ? rcv[kt][j][1] : own[kt][2 * j][1];
      t.u[2] = hi ? own[kt][2 * j + 1][0] : rcv[kt][j][0];
      t.u[3] = hi ? own[kt][2 * j + 1][1] : rcv[kt][j][1];
      pb[ks] = t.v;
    }

    // ---- PV as O^T = V^T · P^T : A = VT rows (d), B = P^T ----
#pragma unroll
    for (int dt = 0; dt < 4; ++dt) {
      const uint32_t vbase = (uint32_t)(VTOFF + (dt * 32 + ql) * VSTRIDE + hi * 16);
#pragma unroll
      for (int ks = 0; ks < 4; ++ks) {
        bf16x8 a = *(const bf16x8*)(smem + vbase + ks * 32);
        o[dt] = __builtin_amdgcn_mfma_f32_32x32x16_bf16(a, pb[ks], o[dt], 0, 0, 0);
      }
    }
  }

  // ---- epilogue: O^T acc -> O[q][d], normalize; d = 32dt + 8q2 + 4hi + i ----
  const float invl = 1.0f / l_r;
  float* op = O + (size_t)(b * Sn + qg) * Dn;
#pragma unroll
  for (int dt = 0; dt < 4; ++dt) {
#pragma unroll
    for (int q2 = 0; q2 < 4; ++q2) {
      float4 v;
      v.x = o[dt][4 * q2 + 0] * invl;
      v.y = o[dt][4 * q2 + 1] * invl;
      v.z = o[dt][4 * q2 + 2] * invl;
      v.w = o[dt][4 * q2 + 3] * invl;
      *(float4*)(op + dt * 32 + q2 * 8 + hi * 4) = v;
    }
  }
}

extern "C" void kernel_launch(void* const* d_in, const int* in_sizes, int n_in,
                              void* d_out, int out_size, void* d_ws, size_t ws_size,
                              hipStream_t stream) {
  (void)in_sizes; (void)n_in; (void)d_ws; (void)ws_size; (void)out_size;
  const float* Q = (const float*)d_in[0];
  const float* K = (const float*)d_in[1];
  const float* V = (const float*)d_in[2];
  float* O = (float*)d_out;
  dim3 grid(Sn / QBLK, Bn, 1);
  attn_fwd<<<grid, dim3(NTHR, 1, 1), 0, stream>>>(Q, K, V, O);
}

// Round 8
// 174.227 us; speedup vs baseline: 1.8150x; 1.0736x over previous
//
#include <hip/hip_runtime.h>
#include <stdint.h>

#define Bn 16
#define Sn 2048
#define Dn 128
#define QBLK 64
#define KVBLK 64
#define NTHR 256

typedef __attribute__((ext_vector_type(4))) float f32x4;
typedef __attribute__((ext_vector_type(16))) float f32x16;
typedef __attribute__((ext_vector_type(8))) short bf16x8;   // 8 bf16 = 4 VGPRs
typedef __attribute__((ext_vector_type(2))) unsigned int u32x2;

// LDS: two independent half-block buffers (KV-split), 34304 B each:
//  K  : [64] rows stride 264 B  byte(k,d) = k*264 + 2d   (2-way banks, free)
//  VT : [128] rows stride 136 B byte(d,k) = d*136 + 2k   (2-way banks)
// End-of-kernel exchange regions overlay the buffers (post-loop only).
#define KSTRIDE 264
#define VTOFF 16896
#define VSTRIDE 136
#define HBUF 34304
#define SMEM_BYTES (2 * HBUF)   // 68608

__device__ __forceinline__ uint32_t f2bf_u(float f) {   // fp32 -> bf16 bits, RNE
  uint32_t x = __float_as_uint(f);
  return (x + 0x7fffu + ((x >> 16) & 1u)) >> 16;
}
__device__ __forceinline__ uint32_t pk2(float a, float b) {
  return f2bf_u(a) | (f2bf_u(b) << 16);
}

__global__ __launch_bounds__(NTHR, 2) void attn_fwd(
    const float* __restrict__ Q, const float* __restrict__ K,
    const float* __restrict__ V, float* __restrict__ O) {
  __shared__ uint4 smem_[SMEM_BYTES / 16];
  char* smem = (char*)smem_;

  const int tid = threadIdx.x;
  const int lane = tid & 63;
  const int w = tid >> 6;        // wave 0..3
  const int h = w >> 1;          // KV half (== tid>>7)
  const int qw = w & 1;          // q sub-tile 0/1
  const int hi = lane >> 5;      // half-wave 0/1
  const int ql = lane & 31;      // q / k-row / d-row selector
  const int ht = tid & 127;      // thread within half-block
  const int b = blockIdx.y;
  const int q0 = blockIdx.x * QBLK;
  const int qg = q0 + qw * 32 + ql;
  const uint32_t hb = (uint32_t)h * HBUF;

  // ---- Q in registers: B-operand of swapped QK^T. col=q=lane&31, kd=8*hi+j ----
  const float qscale = 0.08838834764831845f * 1.44269504088896340736f; // 1/sqrt(128)*log2e
  bf16x8 qf[8];
  {
    const float* qrow = Q + (size_t)(b * Sn + qg) * Dn;
#pragma unroll
    for (int dk = 0; dk < 8; ++dk) {
      const int d0 = dk * 16 + hi * 8;
      const float4 a = *(const float4*)(qrow + d0);
      const float4 d = *(const float4*)(qrow + d0 + 4);
      bf16x8 q8;
      q8[0] = (short)f2bf_u(a.x * qscale); q8[1] = (short)f2bf_u(a.y * qscale);
      q8[2] = (short)f2bf_u(a.z * qscale); q8[3] = (short)f2bf_u(a.w * qscale);
      q8[4] = (short)f2bf_u(d.x * qscale); q8[5] = (short)f2bf_u(d.y * qscale);
      q8[6] = (short)f2bf_u(d.z * qscale); q8[7] = (short)f2bf_u(d.w * qscale);
      qf[dk] = q8;
    }
  }

  // O^T accumulators: o[dt] = D-tile dt (32 d-rows x 32 q-cols), col=q=lane&31
  f32x16 o[4];
#pragma unroll
  for (int dt = 0; dt < 4; ++dt) {
#pragma unroll
    for (int j = 0; j < 16; ++j) o[dt][j] = 0.f;
  }
  float m_r = -1.0e30f, l_r = 0.f;

  const float4* Kg4 = (const float4*)(K + (size_t)b * Sn * Dn);
  const float* Vg_base = V + (size_t)b * Sn * Dn;

  for (int t = 0; t < 16; ++t) {
    const int kv = h * (Sn / 2) + t * KVBLK;
    __syncthreads();   // everyone done reading previous tile

    // ---- stage K: [64][128] fp32 -> bf16 rows @ stride 264 (128 thr/half) ----
    {
      const int kvrow4 = kv * (Dn / 4);
#pragma unroll
      for (int it = 0; it < 16; ++it) {
        const int gr = it * 128 + ht;    // 8B granule id 0..2047
        const int k = gr >> 5;
        const int dg = gr & 31;
        float4 kvv = Kg4[kvrow4 + k * 32 + dg];
        u32x2 wv;
        wv.x = pk2(kvv.x, kvv.y);
        wv.y = pk2(kvv.z, kvv.w);
        *(u32x2*)(smem + hb + k * KSTRIDE + dg * 8) = wv;
      }
    }
    // ---- stage V transposed: VT[d][k], d = ht, 8 uint4 stores ----
    {
      const float* Vg = Vg_base + (size_t)kv * Dn;
#pragma unroll
      for (int it = 0; it < 8; ++it) {
        const int k0 = it * 8;
        uint4 pk;
        {
          float v0 = Vg[(k0 + 0) * Dn + ht], v1 = Vg[(k0 + 1) * Dn + ht];
          float v2 = Vg[(k0 + 2) * Dn + ht], v3 = Vg[(k0 + 3) * Dn + ht];
          float v4 = Vg[(k0 + 4) * Dn + ht], v5 = Vg[(k0 + 5) * Dn + ht];
          float v6 = Vg[(k0 + 6) * Dn + ht], v7 = Vg[(k0 + 7) * Dn + ht];
          pk.x = pk2(v0, v1); pk.y = pk2(v2, v3);
          pk.z = pk2(v4, v5); pk.w = pk2(v6, v7);
        }
        *(uint4*)(smem + hb + VTOFF + ht * VSTRIDE + k0 * 2) = pk;
      }
    }
    __syncthreads();

    // ---- swapped QK^T: S^T[k][q] = K·Q^T, two 32x32 tiles over k ----
    f32x16 s0, s1;
#pragma unroll
    for (int j = 0; j < 16; ++j) { s0[j] = 0.f; s1[j] = 0.f; }
#pragma unroll
    for (int dk = 0; dk < 8; ++dk) {
      const uint32_t co = (uint32_t)(dk * 32 + hi * 16);
      bf16x8 a0 = *(const bf16x8*)(smem + hb + (ql)*KSTRIDE + co);
      bf16x8 a1 = *(const bf16x8*)(smem + hb + (32 + ql) * KSTRIDE + co);
      s0 = __builtin_amdgcn_mfma_f32_32x32x16_bf16(a0, qf[dk], s0, 0, 0, 0);
      s1 = __builtin_amdgcn_mfma_f32_32x32x16_bf16(a1, qf[dk], s1, 0, 0, 0);
    }
    // lane holds, for q = ql: k = 32*kt + (r&3) + 8*(r>>2) + 4*hi, r = 0..15

    // ---- in-register online softmax (per-lane scalar state) ----
    float x0 = fmaxf(fmaxf(s0[0], s0[1]), fmaxf(s0[2], s0[3]));
    float x1 = fmaxf(fmaxf(s0[4], s0[5]), fmaxf(s0[6], s0[7]));
    float x2 = fmaxf(fmaxf(s0[8], s0[9]), fmaxf(s0[10], s0[11]));
    float x3 = fmaxf(fmaxf(s0[12], s0[13]), fmaxf(s0[14], s0[15]));
    float y0 = fmaxf(fmaxf(s1[0], s1[1]), fmaxf(s1[2], s1[3]));
    float y1 = fmaxf(fmaxf(s1[4], s1[5]), fmaxf(s1[6], s1[7]));
    float y2 = fmaxf(fmaxf(s1[8], s1[9]), fmaxf(s1[10], s1[11]));
    float y3 = fmaxf(fmaxf(s1[12], s1[13]), fmaxf(s1[14], s1[15]));
    float pm = fmaxf(fmaxf(fmaxf(x0, x1), fmaxf(x2, x3)),
                     fmaxf(fmaxf(y0, y1), fmaxf(y2, y3)));
    pm = fmaxf(pm, __shfl_xor(pm, 32, 64));   // combine k-halves

    // defer-max (T13): rescale only when running max grows by > 8
    if (!__all(pm <= m_r + 8.0f)) {
      const float mnew = fmaxf(m_r, pm);
      const float alpha = __builtin_amdgcn_exp2f(m_r - mnew);
      l_r *= alpha;
#pragma unroll
      for (int dt = 0; dt < 4; ++dt) o[dt] *= alpha;
      m_r = mnew;
    }

    float p0[16], p1[16];
#pragma unroll
    for (int j = 0; j < 16; ++j) p0[j] = __builtin_amdgcn_exp2f(s0[j] - m_r);
#pragma unroll
    for (int j = 0; j < 16; ++j) p1[j] = __builtin_amdgcn_exp2f(s1[j] - m_r);
    {
      float r0 = 0.f, r1 = 0.f, r2 = 0.f, r3 = 0.f;
#pragma unroll
      for (int j = 0; j < 4; ++j) {
        r0 += p0[j] + p1[j];
        r1 += p0[4 + j] + p1[4 + j];
        r2 += p0[8 + j] + p1[8 + j];
        r3 += p0[12 + j] + p1[12 + j];
      }
      float rsum = (r0 + r1) + (r2 + r3);
      l_r += rsum + __shfl_xor(rsum, 32, 64);
    }

    // ---- pack P to bf16 + half-exchange with lane^32 -> PV B-fragments ----
    uint32_t own[2][4][2];
#pragma unroll
    for (int m = 0; m < 4; ++m) {
      own[0][m][0] = pk2(p0[4 * m + 0], p0[4 * m + 1]);
      own[0][m][1] = pk2(p0[4 * m + 2], p0[4 * m + 3]);
      own[1][m][0] = pk2(p1[4 * m + 0], p1[4 * m + 1]);
      own[1][m][1] = pk2(p1[4 * m + 2], p1[4 * m + 3]);
    }
    uint32_t rcv[2][2][2];
#pragma unroll
    for (int kt = 0; kt < 2; ++kt)
#pragma unroll
      for (int j = 0; j < 2; ++j)
#pragma unroll
        for (int e = 0; e < 2; ++e) {
          uint32_t sel = hi ? own[kt][2 * j][e] : own[kt][2 * j + 1][e];
          rcv[kt][j][e] = (uint32_t)__shfl_xor((int)sel, 32, 64);
        }
    bf16x8 pb[4];
#pragma unroll
    for (int ks = 0; ks < 4; ++ks) {
      const int kt = ks >> 1, j = ks & 1;
      union { uint32_t u[4]; bf16x8 v; } tt;
      tt.u[0] = hi ? rcv[kt][j][0] : own[kt][2 * j][0];
      tt.u[1] = hi ? rcv[kt][j][1] : own[kt][2 * j][1];
      tt.u[2] = hi ? own[kt][2 * j + 1][0] : rcv[kt][j][0];
      tt.u[3] = hi ? own[kt][2 * j + 1][1] : rcv[kt][j][1];
      pb[ks] = tt.v;
    }

    // ---- PV as O^T = V^T · P^T : A = VT rows (d), B = P^T ----
#pragma unroll
    for (int dt = 0; dt < 4; ++dt) {
      const uint32_t vbase =
          (uint32_t)(hb + VTOFF + (dt * 32 + ql) * VSTRIDE + hi * 16);
#pragma unroll
      for (int ks = 0; ks < 4; ++ks) {
        bf16x8 a = *(const bf16x8*)(smem + vbase + ks * 32);
        o[dt] = __builtin_amdgcn_mfma_f32_32x32x16_bf16(a, pb[ks], o[dt], 0, 0, 0);
      }
    }
  }

  // ---- merge the two KV-half partials in LDS, then store ----
  __syncthreads();               // all waves done with main loop
  char* xch = smem + qw * 17408; // per-q-subtile exchange region (16896 B used)
  if (h) {                       // KV-half 1: writer
#pragma unroll
    for (int dt = 0; dt < 4; ++dt) {
#pragma unroll
      for (int q2 = 0; q2 < 4; ++q2) {
        float4 v;
        v.x = o[dt][4 * q2 + 0]; v.y = o[dt][4 * q2 + 1];
        v.z = o[dt][4 * q2 + 2]; v.w = o[dt][4 * q2 + 3];
        *(float4*)(xch + (dt * 4 + q2) * 1024 + lane * 16) = v;
      }
    }
    *(float2*)(xch + 16384 + lane * 8) = make_float2(m_r, l_r);
  }
  __syncthreads();
  if (!h) {                      // KV-half 0: merger + storer
    const float2 ml1 = *(const float2*)(xch + 16384 + lane * 8);
    const float M = fmaxf(m_r, ml1.x);
    float w0 = __builtin_amdgcn_exp2f(m_r - M);
    float w1 = __builtin_amdgcn_exp2f(ml1.x - M);
    const float inv = 1.0f / (l_r * w0 + ml1.y * w1);
    w0 *= inv; w1 *= inv;
    float* op = O + (size_t)(b * Sn + qg) * Dn;
#pragma unroll
    for (int dt = 0; dt < 4; ++dt) {
#pragma unroll
      for (int q2 = 0; q2 < 4; ++q2) {
        const float4 o1 = *(const float4*)(xch + (dt * 4 + q2) * 1024 + lane * 16);
        float4 v;
        v.x = o[dt][4 * q2 + 0] * w0 + o1.x * w1;
        v.y = o[dt][4 * q2 + 1] * w0 + o1.y * w1;
        v.z = o[dt][4 * q2 + 2] * w0 + o1.z * w1;
        v.w = o[dt][4 * q2 + 3] * w0 + o1.w * w1;
        *(float4*)(op + dt * 32 + q2 * 8 + hi * 4) = v;
      }
    }
  }
}

extern "C" void kernel_launch(void* const* d_in, const int* in_sizes, int n_in,
                              void* d_out, int out_size, void* d_ws, size_t ws_size,
                              hipStream_t stream) {
  (void)in_sizes; (void)n_in; (void)d_ws; (void)ws_size; (void)out_size;
  const float* Q = (const float*)d_in[0];
  const float* K = (const float*)d_in[1];
  const float* V = (const float*)d_in[2];
  float* O = (float*)d_out;
  dim3 grid(Sn / QBLK, Bn, 1);
  attn_fwd<<<grid, dim3(NTHR, 1, 1), 0, stream>>>(Q, K, V, O);
}